// Round 1
// baseline (7450.852 us; speedup 1.0000x reference)
//
#include <hip/hip_runtime.h>
#include <math.h>

namespace {
constexpr int LDIM   = 128;
constexpr int HCHUNK = 16;
constexpr int CTILE  = 64;
constexpr int RPAD   = 132;            // padded row stride for sh_in (16B-aligned rows)
constexpr int WROW   = CTILE * 3;      // 192 floats of W per h per c-tile
constexpr int WPAD   = WROW + 1;       // +1 pad: h-rows land in different banks
constexpr int COUT   = 256;
constexpr int NCHUNK = COUT / HCHUNK;  // 16 h-chunks
}

// out[n][h][l] (+= existing if fuse) = [tanh]( sum_{c,k} in[n][c][l+k-1] * w[h][c][k] )
// in == nullptr -> conv term is zero (t==0 step).
__global__ __launch_bounds__(256, 2)
void conv_rnn_step(const float* __restrict__ in, long in_stride,
                   const float* __restrict__ w, int Cin,
                   float* __restrict__ out, long out_stride,
                   int fuse)
{
    __shared__ float sh_in[CTILE * RPAD];   // 33792 B
    __shared__ float sh_w[HCHUNK * WPAD];   // 12352 B

    const int tid = threadIdx.x;
    const int n   = blockIdx.x / NCHUNK;
    const int h0  = (blockIdx.x % NCHUNK) * HCHUNK;
    const int l_g = tid & 15;    // 16 l-groups of 8
    const int h_i = tid >> 4;    // 16 h per block
    const int l8  = l_g * 8;

    float acc[8];
#pragma unroll
    for (int j = 0; j < 8; ++j) acc[j] = 0.f;

    if (in != nullptr) {
        const float* inp = in + (long)n * in_stride;
        const float* wp  = w + (long)h0 * Cin * 3;
        const int ntile  = Cin / CTILE;
        for (int ct = 0; ct < ntile; ++ct) {
            __syncthreads();
            // stage input tile: rows c = ct*CTILE + r, padded l in [-1, 130]
            for (int i = tid; i < CTILE * RPAD; i += 256) {
                const int r = i / RPAD;
                const int l = (i - r * RPAD) - 1;
                float v = 0.f;
                if (l >= 0 && l < LDIM)
                    v = inp[(long)(ct * CTILE + r) * LDIM + l];
                sh_in[i] = v;
            }
            // stage weight slice: HCHUNK h-rows x 192 contiguous floats
            for (int i = tid; i < HCHUNK * WROW; i += 256) {
                const int hh = i / WROW;
                const int q  = i - hh * WROW;
                sh_w[hh * WPAD + q] = wp[((long)hh * Cin + ct * CTILE) * 3 + q];
            }
            __syncthreads();
            const float* wrow = &sh_w[h_i * WPAD];
#pragma unroll 2
            for (int r = 0; r < CTILE; ++r) {
                const float* row = &sh_in[r * RPAD + l8];  // 16B aligned
                float v[10];
#pragma unroll
                for (int d = 0; d < 10; ++d) v[d] = row[d];
                const float w0 = wrow[r * 3 + 0];
                const float w1 = wrow[r * 3 + 1];
                const float w2 = wrow[r * 3 + 2];
#pragma unroll
                for (int j = 0; j < 8; ++j)
                    acc[j] += w0 * v[j] + w1 * v[j + 1] + w2 * v[j + 2];
            }
        }
    }

    float* op = out + (long)n * out_stride + (long)(h0 + h_i) * LDIM + l8;
    if (fuse) {
#pragma unroll
        for (int j = 0; j < 8; ++j)
            op[j] = tanhf(acc[j] + op[j]);
    } else {
#pragma unroll
        for (int j = 0; j < 8; ++j)
            op[j] = acc[j];
    }
}

extern "C" void kernel_launch(void* const* d_in, const int* in_sizes, int n_in,
                              void* d_out, int out_size, void* d_ws, size_t ws_size,
                              hipStream_t stream)
{
    const float* x   = (const float*)d_in[0];   // [B,T,C,L] fp32
    const float* W_i = (const float*)d_in[1];   // [H,C,3]
    const float* W_h = (const float*)d_in[2];   // [H,H,3]
    float* out = (float*)d_out;                 // [B,T,H,L] fp32

    const int B = 16, T = 64, C = 128, H = 256, L = 128;
    const long HL  = (long)H * L;    // 32768
    const long THL = (long)T * HL;   // 2097152

    // Phase 1: Z[b,t] = conv_i(x[b,t]) for all (b,t) in parallel, written into out.
    conv_rnn_step<<<B * T * NCHUNK, 256, 0, stream>>>(
        x, (long)C * L, W_i, C, out, HL, 0);

    // Phase 2: sequential recurrence, in place:
    //   out[b,t] = tanh(out[b,t] + conv_h(out[b,t-1]))
    for (int t = 0; t < T; ++t) {
        const float* hin = (t == 0) ? nullptr : (out + (long)(t - 1) * HL);
        conv_rnn_step<<<B * NCHUNK, 256, 0, stream>>>(
            hin, THL, W_h, H, out + (long)t * HL, THL, 1);
    }
}

// Round 2
// 1141.670 us; speedup vs baseline: 6.5263x; 6.5263x over previous
//
#include <hip/hip_runtime.h>
#include <math.h>

typedef _Float16 f16;
typedef _Float16 f16x4 __attribute__((ext_vector_type(4)));
typedef _Float16 f16x8 __attribute__((ext_vector_type(8)));
typedef float f32x4 __attribute__((ext_vector_type(4)));

#define LDIM 128
#define HOUT 256

// LDS: act_t[plane][r=0..65][c=0..63] f16, row stride 128 B, XOR-swizzled 16B granules.
// plane 0 = hi, plane 1 = lo. plane stride = 66*128 = 8448 B. total 16896 B.
__device__ __forceinline__ int lds_off(int plane, int r, int c) {
    return plane * 8448 + r * 128 + ((((c >> 3) ^ (r & 7)) << 4)) + (c & 7) * 2;
}

__device__ __forceinline__ float tanh_fast(float x) {
    float a = fabsf(x);
    float e = __expf(-2.0f * a);
    float r = (1.0f - e) / (1.0f + e);   // tanh(a), a >= 0, e in (0,1] -> stable
    return copysignf(r, x);
}

// Wt[k][h][c] (f16) <- W[h][c][k] (f32)
__global__ void prep_w(const float* __restrict__ w, f16* __restrict__ wt, int Cin) {
    int idx = blockIdx.x * 256 + threadIdx.x;
    int hc = HOUT * Cin;
    if (idx >= 3 * hc) return;
    int k = idx / hc;
    int r = idx - k * hc;
    int h = r / Cin;
    int c = r - h * Cin;
    wt[idx] = (f16)w[((long)h * Cin + c) * 3 + k];
}

// out[n][h][l] (raw, or fused tanh(acc+out)) = sum_{c,s} Wt[s][h][c] * act[n][c][l+s-1]
// Grid: n_count * 8 blocks; bid -> n = bid>>3, h-chunk = (bid>>1)&3 (64 h), l-chunk = bid&1 (64 l).
// Block: 256 thr = 4 waves, wave-tile 32h x 32l. act == nullptr -> conv term is 0.
__global__ __launch_bounds__(256, 2)
void conv_mfma(const float* __restrict__ act, long act_nstride,
               const f16* __restrict__ wt, int Cin,
               float* __restrict__ out, long out_nstride, int fuse)
{
    __shared__ __align__(16) char smem[16896];
    const int tid  = threadIdx.x;
    const int lane = tid & 63;
    const int wid  = tid >> 6;
    const int wh   = wid >> 1, wl = wid & 1;
    const int bid  = blockIdx.x;
    const int n    = bid >> 3;
    const int h0   = ((bid >> 1) & 3) * 64;
    const int Lb   = (bid & 1) * 64;
    const int l16  = lane & 15, g = lane >> 4;

    f32x4 acc[2][2] = {};

    if (act != nullptr) {
        const float* actn = act + (long)n * act_nstride;
        const int nct = Cin >> 6;
        for (int ct = 0; ct < nct; ++ct) {
            const int c0 = ct << 6;

            // ---- A-frags: Wt[s][h0+wh*32+hf*16+row][c0+kk*32+g*8 ..+7], global b128 (L2-hot)
            f16x8 afr[3][2][2];
#pragma unroll
            for (int s = 0; s < 3; ++s)
#pragma unroll
                for (int kk = 0; kk < 2; ++kk)
#pragma unroll
                    for (int hf = 0; hf < 2; ++hf) {
                        int hh = h0 + wh * 32 + hf * 16 + l16;
                        long off = ((long)(s * HOUT + hh)) * Cin + c0 + kk * 32 + g * 8;
                        afr[s][kk][hf] = *(const f16x8*)(wt + off);
                    }

            __syncthreads();   // previous tile's reads done

            // ---- stage act tile: transpose + fp32 -> f16 hi/lo split
            // edge rows r=0 (l=Lb-1) and r=65 (l=Lb+64), zero-padded
            if (tid < 128) {
                int cl = tid & 63, e = tid >> 6;
                int r  = (e & 1) ? 65 : 0;
                int lg = Lb + r - 1;
                float v = ((unsigned)lg < 128u) ? actn[(long)(c0 + cl) * LDIM + lg] : 0.0f;
                f16 hi = (f16)v;
                f16 lo = (f16)(v - (float)hi);
                *(f16*)(smem + lds_off(0, r, cl)) = hi;
                *(f16*)(smem + lds_off(1, r, cl)) = lo;
            }
            // main rows 1..64: thread = (c4 = tid>>4) x (rb = tid&15); 4c x 4l micro-tile
            {
                const int c4 = tid >> 4, rb = tid & 15;
                const int cc = c0 + c4 * 4;
                const int lg = Lb + rb * 4;
                f32x4 v[4];
#pragma unroll
                for (int ci = 0; ci < 4; ++ci)
                    v[ci] = *(const f32x4*)(actn + (long)(cc + ci) * LDIM + lg);
#pragma unroll
                for (int i = 0; i < 4; ++i) {
                    int r = rb * 4 + i + 1;
                    f16x4 hi, lo;
#pragma unroll
                    for (int ci = 0; ci < 4; ++ci) {
                        float x = v[ci][i];
                        f16 h   = (f16)x;
                        hi[ci]  = h;
                        lo[ci]  = (f16)(x - (float)h);
                    }
                    *(f16x4*)(smem + lds_off(0, r, c4 * 4)) = hi;
                    *(f16x4*)(smem + lds_off(1, r, c4 * 4)) = lo;
                }
            }
            __syncthreads();

            // ---- compute: 3 shifts x 2 k-steps; B-frags from swizzled LDS
#pragma unroll
            for (int s = 0; s < 3; ++s) {
#pragma unroll
                for (int kk = 0; kk < 2; ++kk) {
                    f16x8 bfr[2][2];
#pragma unroll
                    for (int lf = 0; lf < 2; ++lf) {
                        int l = wl * 32 + lf * 16 + l16;
                        int r = l + s;
                        int G = kk * 4 + g;
                        int base = r * 128 + (((G ^ (r & 7)) << 4));
#pragma unroll
                        for (int pl = 0; pl < 2; ++pl)
                            bfr[lf][pl] = *(const f16x8*)(smem + pl * 8448 + base);
                    }
#pragma unroll
                    for (int hf = 0; hf < 2; ++hf)
#pragma unroll
                        for (int lf = 0; lf < 2; ++lf) {
                            acc[hf][lf] = __builtin_amdgcn_mfma_f32_16x16x32_f16(
                                afr[s][kk][hf], bfr[lf][0], acc[hf][lf], 0, 0, 0);
                            acc[hf][lf] = __builtin_amdgcn_mfma_f32_16x16x32_f16(
                                afr[s][kk][hf], bfr[lf][1], acc[hf][lf], 0, 0, 0);
                        }
                }
            }
        }
    }

    // ---- epilogue: C[row=g*4+vv][col=l16] per 16x16 frag
    float* outn = out + (long)n * out_nstride;
#pragma unroll
    for (int hf = 0; hf < 2; ++hf)
#pragma unroll
        for (int lf = 0; lf < 2; ++lf)
#pragma unroll
            for (int vv = 0; vv < 4; ++vv) {
                int hh = h0 + wh * 32 + hf * 16 + g * 4 + vv;
                int ll = Lb + wl * 32 + lf * 16 + l16;
                long idx = (long)hh * LDIM + ll;
                float val = acc[hf][lf][vv];
                if (fuse) val = tanh_fast(val + outn[idx]);
                outn[idx] = val;
            }
}

extern "C" void kernel_launch(void* const* d_in, const int* in_sizes, int n_in,
                              void* d_out, int out_size, void* d_ws, size_t ws_size,
                              hipStream_t stream)
{
    const float* x   = (const float*)d_in[0];   // [B=16][T=64][C=128][L=128]
    const float* W_i = (const float*)d_in[1];   // [256][128][3]
    const float* W_h = (const float*)d_in[2];   // [256][256][3]
    float* out = (float*)d_out;                 // [16][64][256][128]

    f16* wt_i = (f16*)d_ws;                                  // 3*256*128 f16 = 196608 B
    f16* wt_h = (f16*)((char*)d_ws + 3L * 256 * 128 * 2);    // 3*256*256 f16 = 393216 B

    prep_w<<<384, 256, 0, stream>>>(W_i, wt_i, 128);
    prep_w<<<768, 256, 0, stream>>>(W_h, wt_h, 256);

    const long HL  = 256L * 128;   // 32768
    const long THL = 64L * HL;     // per-b stride

    // Phase 1: Z = conv_i(x) for all (b,t); n = b*T+t, 1024 n-slices * 8 blocks
    conv_mfma<<<8192, 256, 0, stream>>>(x, 128L * 128, wt_i, 128, out, HL, 0);

    // Phase 2: h_t = tanh(Z_t + conv_h(h_{t-1})), in place; n = b, 16 n-slices * 8 blocks
    for (int t = 0; t < 64; ++t) {
        const float* hp = (t == 0) ? nullptr : (out + (long)(t - 1) * HL);
        conv_mfma<<<128, 256, 0, stream>>>(hp, THL, wt_h, 256, out + (long)t * HL, THL, 1);
    }
}

// Round 3
// 762.081 us; speedup vs baseline: 9.7770x; 1.4981x over previous
//
#include <hip/hip_runtime.h>
#include <math.h>

typedef _Float16 f16;
typedef _Float16 f16x8 __attribute__((ext_vector_type(8)));
typedef float f32x4 __attribute__((ext_vector_type(4)));

#define LDIM 128
#define HOUT 256

__device__ __forceinline__ float tanh_fast(float x) {
    float a = fabsf(x);
    float e = __expf(-2.0f * a);
    float r = (1.0f - e) / (1.0f + e);   // tanh(|x|), stable
    return copysignf(r, x);
}

// Wt[k][h][c] (f16) <- W[h][c][k] (f32), both weight tensors in one launch
__global__ void prep_w(const float* __restrict__ wi, f16* __restrict__ wti,
                       const float* __restrict__ wh, f16* __restrict__ wth)
{
    int idx = blockIdx.x * 256 + threadIdx.x;
    const int ni = 3 * HOUT * 128;
    if (idx < ni) {
        int k = idx / (HOUT * 128);
        int r = idx - k * (HOUT * 128);
        int h = r >> 7, c = r & 127;
        wti[idx] = (f16)wi[(h * 128 + c) * 3 + k];
    } else {
        int j = idx - ni;
        if (j >= 3 * HOUT * 256) return;
        int k = j / (HOUT * 256);
        int r = j - k * (HOUT * 256);
        int h = r >> 8, c = r & 255;
        wth[j] = (f16)wh[(h * 256 + c) * 3 + k];
    }
}

// ---------------- Phase 1: Z[n][h][l] = conv_i(x[n]) for all n = b*T+t ----------------
// grid 8192: n = bid>>3, h0 = ((bid>>1)&3)*64, Lb = (bid&1)*64. 4 waves, wave tile 32h x 32l.
// LDS: [pl=2][r=0..65][c=0..127] f16, row 256 B, plane 16896 B, 16B-granule XOR swizzle.
__global__ __launch_bounds__(256, 2)
void conv_i_all(const float* __restrict__ x, const f16* __restrict__ wt,
                float* __restrict__ out)
{
    __shared__ __align__(16) char smem[33792];
    const int tid = threadIdx.x;
    const int lane = tid & 63, wid = tid >> 6;
    const int wh = wid >> 1, wl = wid & 1;
    const int n  = blockIdx.x >> 3;
    const int h0 = ((blockIdx.x >> 1) & 3) * 64;
    const int Lb = (blockIdx.x & 1) * 64;
    const int l16 = lane & 15, g = lane >> 4;

    const float* actn = x + (long)n * (128 * LDIM);

    // stage main rows r=1..64 (l = Lb + r - 1): thread = c-group (tid>>4)*8 x l-quad (tid&15)*4
    {
        const int c4 = tid >> 4;
        const int rb = tid & 15;
        const int lg = Lb + rb * 4;
        f32x4 v[8];
#pragma unroll
        for (int ci = 0; ci < 8; ++ci)
            v[ci] = *(const f32x4*)(actn + (c4 * 8 + ci) * LDIM + lg);
#pragma unroll
        for (int i = 0; i < 4; ++i) {
            int r = rb * 4 + i + 1;
            f16x8 hi, lo;
#pragma unroll
            for (int ci = 0; ci < 8; ++ci) {
                float xx = v[ci][i];
                f16 h = (f16)xx;
                hi[ci] = h;
                lo[ci] = (f16)(xx - (float)h);
            }
            int base = r * 256 + ((c4 ^ (r & 7)) << 4);
            *(f16x8*)(smem + base) = hi;
            *(f16x8*)(smem + 16896 + base) = lo;
        }
        // edge rows r=0 (l=Lb-1), r=65 (l=Lb+64), zero-padded
        int cl = tid & 127, e = tid >> 7;
        int r = e ? 65 : 0;
        int lg2 = Lb + r - 1;
        float xx = ((unsigned)lg2 < 128u) ? actn[cl * LDIM + lg2] : 0.f;
        f16 h = (f16)xx;
        f16 lo = (f16)(xx - (float)h);
        int off = r * 256 + ((((cl >> 3) ^ (r & 7)) << 4)) + (cl & 7) * 2;
        *(f16*)(smem + off) = h;
        *(f16*)(smem + 16896 + off) = lo;
    }
    __syncthreads();

    f32x4 acc[2][2] = {};
#pragma unroll
    for (int kk = 0; kk < 4; ++kk) {
        f16x8 afr[3][2];
#pragma unroll
        for (int s = 0; s < 3; ++s)
#pragma unroll
            for (int hf = 0; hf < 2; ++hf) {
                int hh = h0 + wh * 32 + hf * 16 + l16;
                afr[s][hf] = *(const f16x8*)(wt + ((s * HOUT + hh) << 7) + kk * 32 + g * 8);
            }
#pragma unroll
        for (int s = 0; s < 3; ++s) {
            f16x8 bfr[2][2];
#pragma unroll
            for (int lf = 0; lf < 2; ++lf) {
                int r = wl * 32 + lf * 16 + l16 + s;
                int base = r * 256 + ((((kk * 4 + g) ^ (r & 7)) << 4));
                bfr[lf][0] = *(const f16x8*)(smem + base);
                bfr[lf][1] = *(const f16x8*)(smem + 16896 + base);
            }
#pragma unroll
            for (int hf = 0; hf < 2; ++hf)
#pragma unroll
                for (int lf = 0; lf < 2; ++lf) {
                    acc[hf][lf] = __builtin_amdgcn_mfma_f32_16x16x32_f16(
                        afr[s][hf], bfr[lf][0], acc[hf][lf], 0, 0, 0);
                    acc[hf][lf] = __builtin_amdgcn_mfma_f32_16x16x32_f16(
                        afr[s][hf], bfr[lf][1], acc[hf][lf], 0, 0, 0);
                }
        }
    }

    float* outn = out + (long)n * (HOUT * LDIM);
#pragma unroll
    for (int hf = 0; hf < 2; ++hf)
#pragma unroll
        for (int lf = 0; lf < 2; ++lf)
#pragma unroll
            for (int vv = 0; vv < 4; ++vv) {
                int hh = h0 + wh * 32 + hf * 16 + g * 4 + vv;
                int ll = Lb + wl * 32 + lf * 16 + l16;
                outn[hh * LDIM + ll] = acc[hf][lf][vv];
            }
}

// ---------------- Phase 2: one recurrence step, fused add+tanh, in place ----------------
// h_t = tanh(Z_t + conv_h(h_{t-1})); Z_t already in out[.,t,.,.].
// grid 256: n(b) = bid>>4, h0 = ((bid>>2)&3)*64, Lb = (bid&3)*32. Wave tile 32h x 16l.
// LDS: [pl=2][r=0..33][c=0..255] f16, row 512 B, plane 17408 B, swizzled.
__global__ __launch_bounds__(256, 2)
void conv_h_step(const float* __restrict__ hprev, const f16* __restrict__ wt,
                 float* __restrict__ zout)
{
    __shared__ __align__(16) char smem[34816];
    const int tid = threadIdx.x;
    const int lane = tid & 63, wid = tid >> 6;
    const int wh = wid >> 1, wl = wid & 1;
    const int n  = blockIdx.x >> 4;
    const int h0 = ((blockIdx.x >> 2) & 3) * 64;
    const int Lb = (blockIdx.x & 3) * 32;
    const int l16 = lane & 15, g = lane >> 4;
    const long nstride = 64L * HOUT * LDIM;   // T*H*L

    f32x4 acc[2] = {};

    if (hprev != nullptr) {
        const float* actn = hprev + (long)n * nstride;

        // stage main rows r=1..32: thread = c-group (tid>>3)*8 x l-quad (tid&7)*4
        {
            const int c4 = tid >> 3;
            const int rb = tid & 7;
            const int lg = Lb + rb * 4;
            f32x4 v[8];
#pragma unroll
            for (int ci = 0; ci < 8; ++ci)
                v[ci] = *(const f32x4*)(actn + (c4 * 8 + ci) * LDIM + lg);
#pragma unroll
            for (int i = 0; i < 4; ++i) {
                int r = rb * 4 + i + 1;
                f16x8 hi, lo;
#pragma unroll
                for (int ci = 0; ci < 8; ++ci) {
                    float xx = v[ci][i];
                    f16 h = (f16)xx;
                    hi[ci] = h;
                    lo[ci] = (f16)(xx - (float)h);
                }
                int base = r * 512 + ((c4 ^ (r & 7)) << 4);
                *(f16x8*)(smem + base) = hi;
                *(f16x8*)(smem + 17408 + base) = lo;
            }
            // edge rows r=0 (l=Lb-1), r=33 (l=Lb+32); interior chunks read neighbors
            const int cl = tid;   // 0..255
#pragma unroll
            for (int e = 0; e < 2; ++e) {
                int r = e ? 33 : 0;
                int lg2 = Lb + r - 1;
                float xx = ((unsigned)lg2 < 128u) ? actn[cl * LDIM + lg2] : 0.f;
                f16 h = (f16)xx;
                f16 lo = (f16)(xx - (float)h);
                int off = r * 512 + ((((cl >> 3) ^ (r & 7)) << 4)) + (cl & 7) * 2;
                *(f16*)(smem + off) = h;
                *(f16*)(smem + 17408 + off) = lo;
            }
        }
        __syncthreads();

#pragma unroll
        for (int kk = 0; kk < 8; ++kk) {
            f16x8 afr[3][2];
#pragma unroll
            for (int s = 0; s < 3; ++s)
#pragma unroll
                for (int hf = 0; hf < 2; ++hf) {
                    int hh = h0 + wh * 32 + hf * 16 + l16;
                    afr[s][hf] = *(const f16x8*)(wt + ((s * HOUT + hh) << 8) + kk * 32 + g * 8);
                }
#pragma unroll
            for (int s = 0; s < 3; ++s) {
                int r = wl * 16 + l16 + s;
                int base = r * 512 + ((((kk * 4 + g) ^ (r & 7)) << 4));
                f16x8 b0 = *(const f16x8*)(smem + base);
                f16x8 b1 = *(const f16x8*)(smem + 17408 + base);
#pragma unroll
                for (int hf = 0; hf < 2; ++hf) {
                    acc[hf] = __builtin_amdgcn_mfma_f32_16x16x32_f16(afr[s][hf], b0, acc[hf], 0, 0, 0);
                    acc[hf] = __builtin_amdgcn_mfma_f32_16x16x32_f16(afr[s][hf], b1, acc[hf], 0, 0, 0);
                }
            }
        }
    }

    float* outn = zout + (long)n * nstride;
#pragma unroll
    for (int hf = 0; hf < 2; ++hf)
#pragma unroll
        for (int vv = 0; vv < 4; ++vv) {
            int hh = h0 + wh * 32 + hf * 16 + g * 4 + vv;
            int ll = Lb + wl * 16 + l16;
            long idx = (long)hh * LDIM + ll;
            outn[idx] = tanh_fast(acc[hf][vv] + outn[idx]);
        }
}

extern "C" void kernel_launch(void* const* d_in, const int* in_sizes, int n_in,
                              void* d_out, int out_size, void* d_ws, size_t ws_size,
                              hipStream_t stream)
{
    const float* x   = (const float*)d_in[0];   // [16][64][128][128]
    const float* W_i = (const float*)d_in[1];   // [256][128][3]
    const float* W_h = (const float*)d_in[2];   // [256][256][3]
    float* out = (float*)d_out;                 // [16][64][256][128]

    f16* wt_i = (f16*)d_ws;                                  // 3*256*128 f16
    f16* wt_h = (f16*)((char*)d_ws + 3L * 256 * 128 * 2);    // 3*256*256 f16

    prep_w<<<1152, 256, 0, stream>>>(W_i, wt_i, W_h, wt_h);

    const long HL = 256L * 128;

    // Phase 1: Z = conv_i(x) for all (b,t)
    conv_i_all<<<8192, 256, 0, stream>>>(x, wt_i, out);

    // Phase 2: 64 sequential steps, in place
    for (int t = 0; t < 64; ++t) {
        const float* hp = (t == 0) ? nullptr : (out + (long)(t - 1) * HL);
        conv_h_step<<<256, 256, 0, stream>>>(hp, wt_h, out + (long)t * HL);
    }
}